// Round 7
// baseline (759.293 us; speedup 1.0000x reference)
//
#include <hip/hip_runtime.h>

#define NV 16384
#define EH 16256
#define EVV 16256
#define ED 16129
#define NE 48641
#define NT 32258
#define ND 32259
#define OUTERF 32258
#define NWORD 1521   // (NE+31)/32

typedef unsigned int u32;
typedef unsigned short u16;

// ---------------- ws layout ----------------
static __host__ __device__ constexpr size_t al256(size_t x) { return (x + 255) & ~(size_t)255; }
static constexpr size_t OFF_ACC   = 0;                                  // acc[0..6)
static constexpr size_t OFF_R32   = 256;                                // u32[NV]
static constexpr size_t OFF_FVAL  = OFF_R32   + al256(NV * 4);          // f32[ND]
static constexpr size_t OFF_CTV   = OFF_FVAL  + al256(ND * 4);          // u16[NT]
static constexpr size_t OFF_CNTR  = OFF_CTV   + al256(NT * 2);          // u32[NV]
static constexpr size_t OFF_FRK   = OFF_CNTR  + al256(NV * 4);          // u32[ND]
static constexpr size_t OFF_FRV   = OFF_FRK   + al256(ND * 4);          // f32[ND]
static constexpr size_t OFF_DVAL  = OFF_FRV   + al256(ND * 4);          // f32[NE]
static constexpr size_t OFF_EP    = OFF_DVAL  + al256(NE * 4);          // uint2[NE]
static constexpr size_t OFF_EDU   = OFF_EP    + al256(NE * 8);          // uint2[NE]
static constexpr size_t OFF_ISM   = OFF_EDU   + al256(NE * 8);          // u32[NWORD]

__device__ __forceinline__ u32 fmap(float x) {
  u32 u = __float_as_uint(x);
  return (u & 0x80000000u) ? ~u : (u | 0x80000000u);
}
__device__ __forceinline__ float funmap(u32 m) {
  u32 u = (m & 0x80000000u) ? (m & 0x7FFFFFFFu) : ~m;
  return __uint_as_float(u);
}

__device__ __forceinline__ int findh(volatile u16* par, int x) {
  while (true) {
    int p = par[x];
    if (p == x) return x;
    int gp = par[p];
    if (gp == p) return p;
    par[x] = (u16)gp;
    x = gp;
  }
}

// edge eid -> primal endpoints
__device__ __forceinline__ void decode_pe(u32 e, int& eu, int& ev) {
  if (e < EH) { int i = (int)(e / 127u), j = (int)(e - (u32)i * 127u); eu = (i << 7) + j; ev = eu + 1; }
  else if (e < EH + EVV) { int k = (int)(e - EH); eu = k; ev = k + 128; }
  else { int k = (int)(e - EH - EVV); int i = k / 127, j = k - i * 127; eu = (i << 7) + j; ev = eu + 129; }
}
// edge eid -> dual faces
__device__ __forceinline__ void decode_df(u32 e, int& fa, int& fb) {
  if (e < EH) { int i = (int)(e / 127u), j = (int)(e - (u32)i * 127u);
    fa = (i < 127) ? (ED + i * 127 + j) : OUTERF;
    fb = (i >= 1) ? ((i - 1) * 127 + j) : OUTERF; }
  else if (e < EH + EVV) { int k = (int)(e - EH); int i = k >> 7, j = k & 127;
    fa = (j < 127) ? (i * 127 + j) : OUTERF;
    fb = (j >= 1) ? (ED + i * 127 + (j - 1)) : OUTERF; }
  else { int k = (int)(e - EH - EVV); int i = k / 127, j = k - i * 127;
    fa = i * 127 + j; fb = ED + i * 127 + j; }
}

// ---------------- K0: init ----------------
// acc: F[0]=sum dv(all edges), F[1]=sum beta, U[2]=max beta(fmap),
//      F[3]=sum fval(faces), F[4]=sum dv(primal MST)
__global__ void k_init(float* accF, u32* r32, u32* isMSTG) {
  int i = blockIdx.x * 256 + threadIdx.x;
  if (i < 6) accF[i] = 0.f;
  if (i < NV) r32[i] = 0u;
  if (i < NWORD) isMSTG[i] = 0u;
}

// ---------------- K1: vertex ranks (ascending beta, id tiebreak) ----------------
__global__ void k_rankv(const float* __restrict__ beta, u32* r32) {
  int v = blockIdx.x * 256 + threadIdx.x;
  int c = blockIdx.y;
  float bv = beta[v];
  int u0 = c << 10;
  int cnt = 0;
#pragma unroll 8
  for (int u = u0; u < u0 + 1024; ++u) {
    float bu = beta[u];
    cnt += (bu < bv || (bu == bv && u < v)) ? 1 : 0;
  }
  if (cnt) atomicAdd(&r32[v], (u32)cnt);
}

// ---------------- K2: face values + crit vertex + reductions ----------------
__global__ void k_build(const float* __restrict__ beta, const u32* __restrict__ r32,
                        float* fval, u16* ctv, float* accF, u32* accU) {
  __shared__ float ls[4], lm[4];
  int bid = blockIdx.x, tid = threadIdx.x;
  if (bid < 64) {
    int v = (bid << 8) + tid;
    float b = beta[v];
    float s = b, m = b;
    for (int off = 32; off >= 1; off >>= 1) {
      s += __shfl_down(s, off);
      m = fmaxf(m, __shfl_down(m, off));
    }
    int wid = tid >> 6;
    if ((tid & 63) == 0) { ls[wid] = s; lm[wid] = m; }
    __syncthreads();
    if (tid == 0) {
      s = ls[0] + ls[1] + ls[2] + ls[3];
      m = fmaxf(fmaxf(lm[0], lm[1]), fmaxf(lm[2], lm[3]));
      atomicAdd(&accF[1], s);
      atomicMax(&accU[2], fmap(m));
    }
  } else {
    int t = ((bid - 64) << 8) + tid;
    float c = 0.f;
    if (t < NT) {
      int i, j, v0, v1, v2;
      if (t < ED) { i = t / 127; j = t - i * 127; v0 = (i << 7) + j; v1 = v0 + 128; v2 = v0 + 129; } // L
      else { int u = t - ED; i = u / 127; j = u - i * 127; v0 = (i << 7) + j; v1 = v0 + 1; v2 = v0 + 129; } // U
      u32 r0 = r32[v0], r1 = r32[v1], r2 = r32[v2];
      int crit = v0; u32 rm = r0;
      if (r1 < rm) { rm = r1; crit = v1; }
      if (r2 < rm) { rm = r2; crit = v2; }
      float fv = -beta[crit];
      fval[t] = fv;
      ctv[t] = (u16)crit;
      c = fv;
      if (t == 0) fval[OUTERF] = __builtin_inff();
    }
    for (int off = 32; off >= 1; off >>= 1) c += __shfl_down(c, off);
    int wid = tid >> 6;
    if ((tid & 63) == 0) ls[wid] = c;
    __syncthreads();
    if (tid == 0) atomicAdd(&accF[3], ls[0] + ls[1] + ls[2] + ls[3]);
  }
}

// ---------------- K3a: per-vertex crit-face counts into rank buckets ----------------
__global__ void k_cntface(const u16* __restrict__ ctv, const u32* __restrict__ r32, u32* cntR) {
  int v = blockIdx.x * 256 + threadIdx.x;
  int i = v >> 7, j = v & 127;
  int cnt = 0;
  if (i < 127 && j < 127) cnt += (ctv[i * 127 + j] == v);
  if (i >= 1 && j < 127)  cnt += (ctv[(i - 1) * 127 + j] == v);
  if (i >= 1 && j >= 1)   cnt += (ctv[(i - 1) * 127 + (j - 1)] == v);
  if (i < 127 && j < 127) cnt += (ctv[ED + i * 127 + j] == v);
  if (i < 127 && j >= 1)  cnt += (ctv[ED + i * 127 + (j - 1)] == v);
  if (i >= 1 && j >= 1)   cnt += (ctv[ED + (i - 1) * 127 + (j - 1)] == v);
  cntR[r32[v]] = (u32)cnt;
}

// ---------------- K3b: exclusive scan over NV rank buckets (+1: outer face = rank 0) ----------------
__global__ __launch_bounds__(1024) void k_scanR(u32* cntR) {
  __shared__ u32 wsum[16];
  int tid = threadIdx.x;
  u32 loc[16]; u32 s = 0;
#pragma unroll
  for (int k = 0; k < 16; ++k) { u32 c = cntR[(tid << 4) + k]; loc[k] = s; s += c; }
  int lane = tid & 63, wid = tid >> 6;
  u32 incl = s;
  for (int off = 1; off < 64; off <<= 1) {
    u32 o = __shfl_up(incl, off);
    if (lane >= off) incl += o;
  }
  if (lane == 63) wsum[wid] = incl;
  __syncthreads();
  u32 wbase = 0;
  for (int w = 0; w < wid; ++w) wbase += wsum[w];
  u32 base = wbase + incl - s + 1;
#pragma unroll
  for (int k = 0; k < 16; ++k) cntR[(tid << 4) + k] = base + loc[k];
}

// ---------------- K3c: face ranks + rank->value table ----------------
__global__ void k_facerank(const u16* __restrict__ ctv, const u32* __restrict__ r32,
                           const u32* __restrict__ startsR, const float* __restrict__ fval,
                           u32* frk, float* frv) {
  int g = blockIdx.x * 256 + threadIdx.x;
  if (g == 0) { frk[OUTERF] = 0u; frv[0] = __builtin_inff(); }
  if (g >= NT) return;
  int v = ctv[g];
  int i = v >> 7, j = v & 127;
  int local = 0, f;
  if (i < 127 && j < 127) { f = i * 127 + j;             local += (f < g && ctv[f] == v); }
  if (i >= 1 && j < 127)  { f = (i - 1) * 127 + j;       local += (f < g && ctv[f] == v); }
  if (i >= 1 && j >= 1)   { f = (i - 1) * 127 + (j - 1); local += (f < g && ctv[f] == v); }
  if (i < 127 && j < 127) { f = ED + i * 127 + j;        local += (f < g && ctv[f] == v); }
  if (i < 127 && j >= 1)  { f = ED + i * 127 + (j - 1);  local += (f < g && ctv[f] == v); }
  if (i >= 1 && j >= 1)   { f = ED + (i - 1) * 127 + (j - 1); local += (f < g && ctv[f] == v); }
  u32 rk = startsR[r32[v]] + (u32)local;
  frk[g] = rk;
  frv[rk] = fval[g];
}

// ---------------- K4: edge values + packed edge records + total sum ----------------
// eP: (eu|ev<<16, MST key = ((16383-rr)<<17)|e)   [primal Kruskal ascending f]
// eD: (frk[fa]|frk[fb]<<16, dual key = (rr<<17)|e) [dual Kruskal descending f]
__global__ void k_edges(const float* __restrict__ beta, const u32* __restrict__ r32,
                        const u32* __restrict__ frk,
                        float* dvals, uint2* eP, uint2* eD, float* accF) {
  int e = blockIdx.x * 256 + threadIdx.x;
  float dv = 0.f;
  if (e < NE) {
    int eu, ev; decode_pe((u32)e, eu, ev);
    int fa, fb; decode_df((u32)e, fa, fb);
    u32 ru = r32[eu], rv = r32[ev];
    u32 rr = min(ru, rv);
    int cv = (ru <= rv) ? eu : ev;
    dv = -beta[cv];
    dvals[e] = dv;
    eP[e] = make_uint2((u32)eu | ((u32)ev << 16), ((16383u - rr) << 17) | (u32)e);
    eD[e] = make_uint2(frk[fa] | (frk[fb] << 16), (rr << 17) | (u32)e);
  }
  float ds = dv;
  for (int off = 32; off >= 1; off >>= 1) ds += __shfl_down(ds, off);
  if ((threadIdx.x & 63) == 0) atomicAdd(&accF[0], ds);
}

// ---------------- K5: PRIMAL MST (claim-both-roots, owner slots, root-side P2) ----------------
// Exact: winner of either root = min pending edge crossing that component's cut
// (cut property, unique keys => unique MST). Hook chains strictly key-decreasing => acyclic.
__global__ __launch_bounds__(1024) void k_mst(
    const uint2* __restrict__ eP, const float* __restrict__ dvals,
    u32* __restrict__ isMSTG, float* accF) {
  __shared__ u16 parL[NV];        // 32 KB
  __shared__ u32 mtabL[NV];       // 64 KB
  __shared__ u32 live[NWORD];     // 6 KB
  __shared__ int nRem;
  __shared__ float wred[16];
  int tid = threadIdx.x, lane = tid & 63;
  for (int v = tid; v < NV; v += 1024) { parL[v] = (u16)v; mtabL[v] = 0xFFFFFFFFu; }
  for (int w = tid; w < NWORD; w += 1024) live[w] = (w == NWORD - 1) ? 1u : 0xFFFFFFFFu;
  if (tid == 0) nRem = NE;
  float wloc = 0.f;
  __syncthreads();
  for (int round = 0; round < 64; ++round) {
    if (nRem <= 0) break;
    int resolved = 0;
    // P1: live edges claim both roots (no concurrent hooks)
    for (int s = 0; s < 48; ++s) {
      int e = tid + (s << 10);
      if (e >= NE) break;
      if (!((live[e >> 5] >> (e & 31)) & 1u)) continue;
      uint2 pk = eP[e];
      int eu = (int)(pk.x & 0xFFFFu), ev = (int)(pk.x >> 16);
      int ra = findh((volatile u16*)parL, eu);
      int rb = findh((volatile u16*)parL, ev);
      if (ra == rb) {               // cycle edge (non-MST): drop
        atomicAnd(&live[e >> 5], ~(1u << (e & 31)));
        resolved++;
        continue;
      }
      atomicMin(&mtabL[ra], pk.y);
      atomicMin(&mtabL[rb], pk.y);
    }
    __syncthreads();
    // P2: root-side winners commit + hook (exactly-once via other<v rule)
    for (int v = tid; v < NV; v += 1024) {
      u32 kk = mtabL[v];
      if (kk == 0xFFFFFFFFu) continue;
      int e = (int)(kk & 0x1FFFFu);
      uint2 pk = eP[e];
      int eu = (int)(pk.x & 0xFFFFu), ev = (int)(pk.x >> 16);
      int r1 = findh((volatile u16*)parL, eu);
      int r2 = findh((volatile u16*)parL, ev);
      int other = (r1 == v) ? r2 : r1;
      bool both = (mtabL[other] == kk);
      if (both && other < v) continue;   // the other root's thread handles it
      if (both) parL[max(v, other)] = (u16)min(v, other);
      else parL[v] = (u16)other;
      atomicOr(&isMSTG[e >> 5], 1u << (e & 31));
      wloc += dvals[e];
      atomicAnd(&live[e >> 5], ~(1u << (e & 31)));
      resolved++;
    }
    for (int off = 32; off >= 1; off >>= 1) resolved += __shfl_down(resolved, off);
    if (lane == 0 && resolved) atomicSub(&nRem, resolved);
    __syncthreads();
    // P3: reset claims + one compression sweep
    for (int v = tid; v < NV; v += 1024) {
      mtabL[v] = 0xFFFFFFFFu;
      int p = parL[v]; int pp = parL[p];
      if (p != pp) parL[v] = (u16)pp;
    }
    __syncthreads();
  }
  for (int off = 32; off >= 1; off >>= 1) wloc += __shfl_down(wloc, off);
  if (lane == 0) wred[tid >> 6] = wloc;
  __syncthreads();
  if (tid == 0) {
    float s = 0.f;
    for (int w = 0; w < 16; ++w) s += wred[w];
    atomicAdd(&accF[4], s);
  }
}

// ---------------- K6: dual-tree Kruskal pairing + max bar + output ----------------
// live = complement of MST (= dual maxST edges, all merge). Claims by filtration
// key into hashed slot (y & 16383); slot winner commits (younger root y stable:
// only its own winner can hook it). Records only the max bar (sums closed-form).
__global__ __launch_bounds__(1024) void k_pair(
    const uint2* __restrict__ eD, const float* __restrict__ dvals,
    const u32* __restrict__ isMSTG, const float* __restrict__ frv,
    const float* __restrict__ accF, const u32* __restrict__ accU, float* out) {
  __shared__ u16 par[ND + 1];     // 64.5 KB
  __shared__ u32 mt[16384];       // 64 KB
  __shared__ u32 live[NWORD];     // 6 KB
  __shared__ int nRem;
  __shared__ float mred[16];
  int tid = threadIdx.x, lane = tid & 63;
  {
    u32* p32 = (u32*)par;
    for (int v = tid; v < (ND + 1) / 2; v += 1024)
      p32[v] = ((2u * v + 1) << 16) | (2u * v);
  }
  for (int h = tid; h < 16384; h += 1024) mt[h] = 0xFFFFFFFFu;
  for (int w = tid; w < NWORD; w += 1024)
    live[w] = ~isMSTG[w] & ((w == NWORD - 1) ? 1u : 0xFFFFFFFFu);
  if (tid == 0) nRem = NT;
  float lmax = 0.f;
  __syncthreads();
  for (int round = 0; round < 2048; ++round) {
    if (nRem <= 0) break;
    int resolved = 0;
    // P1: live edges claim their younger root's slot
    for (int s = 0; s < 48; ++s) {
      int e = tid + (s << 10);
      if (e >= NE) break;
      if (!((live[e >> 5] >> (e & 31)) & 1u)) continue;
      uint2 dk = eD[e];
      int ya = (int)(dk.x & 0xFFFFu), yb = (int)(dk.x >> 16);
      int ra = findh((volatile u16*)par, ya);
      int rb = findh((volatile u16*)par, yb);
      if (ra == rb) {               // cannot happen for tree edges; defensive
        atomicAnd(&live[e >> 5], ~(1u << (e & 31)));
        resolved++;
        continue;
      }
      int y = max(ra, rb);
      atomicMin(&mt[y & 16383], dk.y);
    }
    __syncthreads();
    // P2: slot winners commit: record bar, hook younger under older
    for (int h = tid; h < 16384; h += 1024) {
      u32 kk = mt[h];
      if (kk == 0xFFFFFFFFu) continue;
      int e = (int)(kk & 0x1FFFFu);
      uint2 dk = eD[e];
      int ya = (int)(dk.x & 0xFFFFu), yb = (int)(dk.x >> 16);
      int ra = findh((volatile u16*)par, ya);
      int rb = findh((volatile u16*)par, yb);
      int y = max(ra, rb), o = min(ra, rb);
      if ((y & 16383) != h) continue;   // defensive (y is stable in practice)
      par[y] = (u16)o;
      lmax = fmaxf(lmax, frv[y] - dvals[e]);
      atomicAnd(&live[e >> 5], ~(1u << (e & 31)));
      resolved++;
    }
    for (int off = 32; off >= 1; off >>= 1) resolved += __shfl_down(resolved, off);
    if (lane == 0 && resolved) atomicSub(&nRem, resolved);
    __syncthreads();
    // P3: reset claims + compress
    for (int h = tid; h < 16384; h += 1024) mt[h] = 0xFFFFFFFFu;
    for (int v = tid; v < ND; v += 1024) {
      int p = par[v]; int pp = par[p];
      if (p != pp) par[v] = (u16)pp;
    }
    __syncthreads();
  }
  // reduce max bar + assemble output
  for (int off = 32; off >= 1; off >>= 1) lmax = fmaxf(lmax, __shfl_down(lmax, off));
  if (lane == 0) mred[tid >> 6] = lmax;
  __syncthreads();
  if (tid == 0) {
    float m = 0.f;
    for (int w = 0; w < 16; ++w) m = fmaxf(m, mred[w]);
    float pms = accF[4];                       // primal MST f-sum
    float loss0 = pms + accF[1] - funmap(accU[2]);
    float sum1 = accF[3] - (accF[0] - pms);    // faces - dual-tree sum
    out[0] = loss0 + sum1 - m;
  }
}

extern "C" void kernel_launch(void* const* d_in, const int* in_sizes, int n_in,
                              void* d_out, int out_size, void* d_ws, size_t ws_size,
                              hipStream_t stream) {
  const float* beta = (const float*)d_in[0];
  float* out = (float*)d_out;
  char* ws = (char*)d_ws;
  float* accF = (float*)(ws + OFF_ACC);
  u32*   accU = (u32*)(ws + OFF_ACC);
  u32* r32 = (u32*)(ws + OFF_R32);
  float* fval = (float*)(ws + OFF_FVAL);
  u16* ctv = (u16*)(ws + OFF_CTV);
  u32* cntR = (u32*)(ws + OFF_CNTR);
  u32* frk = (u32*)(ws + OFF_FRK);
  float* frv = (float*)(ws + OFF_FRV);
  float* dvals = (float*)(ws + OFF_DVAL);
  uint2* eP = (uint2*)(ws + OFF_EP);
  uint2* eD = (uint2*)(ws + OFF_EDU);
  u32* isMSTG = (u32*)(ws + OFF_ISM);

  hipLaunchKernelGGL(k_init, dim3(64), dim3(256), 0, stream, accF, r32, isMSTG);
  hipLaunchKernelGGL(k_rankv, dim3(64, 16), dim3(256), 0, stream, beta, r32);
  hipLaunchKernelGGL(k_build, dim3(191), dim3(256), 0, stream, beta, r32, fval, ctv, accF, accU);
  hipLaunchKernelGGL(k_cntface, dim3(64), dim3(256), 0, stream, ctv, r32, cntR);
  hipLaunchKernelGGL(k_scanR, dim3(1), dim3(1024), 0, stream, cntR);
  hipLaunchKernelGGL(k_facerank, dim3(127), dim3(256), 0, stream, ctv, r32, cntR, fval, frk, frv);
  hipLaunchKernelGGL(k_edges, dim3(191), dim3(256), 0, stream, beta, r32, frk, dvals, eP, eD, accF);
  hipLaunchKernelGGL(k_mst, dim3(1), dim3(1024), 0, stream, eP, dvals, isMSTG, accF);
  hipLaunchKernelGGL(k_pair, dim3(1), dim3(1024), 0, stream, eD, dvals, isMSTG, frv, accF, accU, out);
}